// Round 8
// baseline (951.706 us; speedup 1.0000x reference)
//
#include <hip/hip_runtime.h>

#define NPTS 16384
#define DIN  1024
#define DP   128
#define NS   163
#define NBLK 256         // one wave per block, one block per CU
#define BTHR 64          // NBLK*BTHR = NPTS, 1 point/thread

// ---------------- K1: projection GEMM  R[N,128] = F[N,1024] @ W[1024,128] (f32)
__global__ __launch_bounds__(256) void k_proj(const float* __restrict__ F,
                                              const float* __restrict__ W,
                                              float* __restrict__ R) {
    __shared__ float As[32][36];    // 32 rows x 32 k (+pad, 36 keeps 16B align)
    __shared__ float Bs[32][128];   // 32 k x 128 cols
    const int tid = threadIdx.x;
    const int bm  = blockIdx.x;            // 512 blocks * 32 rows
    const int lr  = tid >> 3;              // A-load row 0..31
    const int lc  = (tid & 7) * 4;         // A-load k-offset
    const int bkr = tid >> 5;              // B-load kk base 0..7
    const int bc  = (tid & 31) * 4;        // B-load col
    const int r0  = (tid >> 5) * 4;        // 0,4,..,28
    const int c0  = (tid & 31) * 4;        // 0,4,..,124

    float acc[4][4] = {};

    for (int k0 = 0; k0 < DIN; k0 += 32) {
        __syncthreads();
        *(float4*)&As[lr][lc] =
            *(const float4*)&F[(size_t)(bm * 32 + lr) * DIN + k0 + lc];
        #pragma unroll
        for (int p = 0; p < 4; ++p) {
            const int kk = bkr + p * 8;
            *(float4*)&Bs[kk][bc] = *(const float4*)&W[(size_t)(k0 + kk) * DP + bc];
        }
        __syncthreads();
        #pragma unroll
        for (int kt = 0; kt < 32; kt += 4) {
            float4 a[4], b[4];
            #pragma unroll
            for (int i = 0; i < 4; ++i) a[i] = *(const float4*)&As[r0 + i][kt];
            #pragma unroll
            for (int j = 0; j < 4; ++j) b[j] = *(const float4*)&Bs[kt + j][c0];
            #pragma unroll
            for (int i = 0; i < 4; ++i) {
                acc[i][0] += a[i].x * b[0].x; acc[i][1] += a[i].x * b[0].y;
                acc[i][2] += a[i].x * b[0].z; acc[i][3] += a[i].x * b[0].w;
                acc[i][0] += a[i].y * b[1].x; acc[i][1] += a[i].y * b[1].y;
                acc[i][2] += a[i].y * b[1].z; acc[i][3] += a[i].y * b[1].w;
                acc[i][0] += a[i].z * b[2].x; acc[i][1] += a[i].z * b[2].y;
                acc[i][2] += a[i].z * b[2].z; acc[i][3] += a[i].z * b[2].w;
                acc[i][0] += a[i].w * b[3].x; acc[i][1] += a[i].w * b[3].y;
                acc[i][2] += a[i].w * b[3].z; acc[i][3] += a[i].w * b[3].w;
            }
        }
    }
    #pragma unroll
    for (int i = 0; i < 4; ++i) {
        float4 v = make_float4(acc[i][0], acc[i][1], acc[i][2], acc[i][3]);
        *(float4*)&R[(size_t)(bm * 32 + r0 + i) * DP + c0] = v;
    }
}

// ---------------- K2: per-row squared norm sq[i] = ||R_i||^2 (wave per row)
__global__ void k_sq(const float* __restrict__ R, float* __restrict__ sq) {
    const int lane = threadIdx.x & 63;
    const int wave = (blockIdx.x * blockDim.x + threadIdx.x) >> 6;  // 0..255
    for (int row = wave; row < NPTS; row += 256) {
        const float a = R[(size_t)row * DP + lane];
        const float b = R[(size_t)row * DP + 64 + lane];
        float v = a * a + b * b;
        #pragma unroll
        for (int off = 32; off; off >>= 1) v += __shfl_xor(v, off);
        if (lane == 0) sq[row] = v;
    }
}

// ---------------- K3a: coalesced partial col sums over 256-row slabs; also clears gmax
__global__ __launch_bounds__(256) void k_colpart(const float* __restrict__ R,
                                                 const float* __restrict__ sq,
                                                 float* __restrict__ part,
                                                 float* __restrict__ part_sq,
                                                 unsigned long long* __restrict__ gmax) {
    const int b = blockIdx.x, tid = threadIdx.x;

    // clear the greedy slots: NS*NBLK = 41728 slots, 16384 threads -> 3 strides
    for (int s = b * 256 + tid; s < NS * NBLK; s += 64 * 256) gmax[s] = 0ull;

    if (tid < DP) {
        float acc = 0.0f;
        const float* p = R + (size_t)b * 256 * DP + tid;
        #pragma unroll 8
        for (int r = 0; r < 256; ++r) acc += p[(size_t)r * DP];
        part[b * DP + tid] = acc;
    } else if (tid < 192) {
        const int lane = tid - 128;   // wave 2: partial sum of sq over the slab
        const float* s = sq + b * 256;
        float v = s[lane] + s[64 + lane] + s[128 + lane] + s[192 + lane];
        #pragma unroll
        for (int off = 32; off; off >>= 1) v += __shfl_xor(v, off);
        if (lane == 0) part_sq[b] = v;
    }
}

// ---------------- K3b: final deterministic reduction of partials
__global__ void k_colfin(const float* __restrict__ part, const float* __restrict__ part_sq,
                         float* __restrict__ tS) {
    const int tid = threadIdx.x;
    if (tid < DP) {
        float acc = 0.0f;
        #pragma unroll 8
        for (int b = 0; b < 64; ++b) acc += part[b * DP + tid];
        tS[tid] = acc;
    } else if (tid == DP) {
        float s = 0.0f;
        #pragma unroll
        for (int b = 0; b < 64; ++b) s += part_sq[b];
        tS[DP] = s;
    }
}

// ---------------- K4: greedy FPS; 1 wave/block, zero LDS, zero __syncthreads
__global__ __launch_bounds__(BTHR, 1) void k_greedy(
    const float* __restrict__ R, const float* __restrict__ sq,
    const float* __restrict__ tS, const float* __restrict__ F,
    unsigned long long* gmax, float* __restrict__ out) {
    const int tid = threadIdx.x;                // 0..63 == lane
    const int bid = blockIdx.x;                 // 0..255
    const int g   = (bid << 6) | tid;           // my point id

    // own projected row in registers (32 x float4 = 128 VGPRs)
    float4 rr[32];
    #pragma unroll
    for (int q = 0; q < 32; ++q) rr[q] = *(const float4*)&R[(size_t)g * DP + q * 4];
    const float sqi = sq[g];

    // anchor0 = sqrt(N*sq_i + S - 2*r_i.t)  (common terms preserve ranking)
    float a0 = 0.f, a1 = 0.f, a2 = 0.f, a3 = 0.f;
    #pragma unroll
    for (int q = 0; q < 32; ++q) {
        const float4 t4 = *(const float4*)&tS[q * 4];
        a0 += rr[q].x * t4.x; a1 += rr[q].y * t4.y;
        a2 += rr[q].z * t4.z; a3 += rr[q].w * t4.w;
    }
    const float S = tS[DP];
    float anchor = sqrtf(fmaxf((float)NPTS * sqi + S - 2.0f * ((a0 + a1) + (a2 + a3)), 0.0f));

    unsigned myidx = 0;

    for (int k = 0; k < NS; ++k) {
        // key = (bits(anchor)<<32) | (~g): max-key == first-occurrence argmax; never 0
        unsigned long long key =
            ((unsigned long long)__float_as_uint(anchor) << 32) |
            (unsigned long long)(0xFFFFFFFFu - (unsigned)g);
        #pragma unroll
        for (int off = 32; off; off >>= 1) {
            const unsigned long long o = __shfl_xor(key, off);
            key = (o > key) ? o : key;
        }
        // publish this block's max directly (no LDS hop, no syncthreads)
        if (tid == 0)
            __hip_atomic_store(&gmax[(size_t)k * NBLK + bid], key,
                               __ATOMIC_RELAXED, __HIP_MEMORY_SCOPE_AGENT);

        // poll all 256 slots: 4 loads/lane, sleep backoff
        const unsigned long long* gs = &gmax[(size_t)k * NBLK];
        unsigned long long v0, v1, v2, v3;
        v0 = __hip_atomic_load(&gs[tid      ], __ATOMIC_RELAXED, __HIP_MEMORY_SCOPE_AGENT);
        v1 = __hip_atomic_load(&gs[tid +  64], __ATOMIC_RELAXED, __HIP_MEMORY_SCOPE_AGENT);
        v2 = __hip_atomic_load(&gs[tid + 128], __ATOMIC_RELAXED, __HIP_MEMORY_SCOPE_AGENT);
        v3 = __hip_atomic_load(&gs[tid + 192], __ATOMIC_RELAXED, __HIP_MEMORY_SCOPE_AGENT);
        while (!__all((v0 != 0ull) & (v1 != 0ull) & (v2 != 0ull) & (v3 != 0ull))) {
            __builtin_amdgcn_s_sleep(1);
            v0 = __hip_atomic_load(&gs[tid      ], __ATOMIC_RELAXED, __HIP_MEMORY_SCOPE_AGENT);
            v1 = __hip_atomic_load(&gs[tid +  64], __ATOMIC_RELAXED, __HIP_MEMORY_SCOPE_AGENT);
            v2 = __hip_atomic_load(&gs[tid + 128], __ATOMIC_RELAXED, __HIP_MEMORY_SCOPE_AGENT);
            v3 = __hip_atomic_load(&gs[tid + 192], __ATOMIC_RELAXED, __HIP_MEMORY_SCOPE_AGENT);
        }

        unsigned long long m = v0;
        if (v1 > m) m = v1;
        if (v2 > m) m = v2;
        if (v3 > m) m = v3;
        #pragma unroll
        for (int off = 32; off; off >>= 1) {
            const unsigned long long o = __shfl_xor(m, off);
            m = (o > m) ? o : m;
        }
        const unsigned idx = 0xFFFFFFFFu - (unsigned)(m & 0xFFFFFFFFull);
        if (k == bid) myidx = idx;   // block k gathers row k at the end

        // anchor = min(anchor, dist(g, idx)); selected row via broadcast loads
        const float sqs = sq[idx];
        const float* rs = &R[(size_t)idx * DP];
        float d0 = 0.f, d1 = 0.f, d2 = 0.f, d3 = 0.f;
        #pragma unroll
        for (int q = 0; q < 32; ++q) {
            const float4 w4 = *(const float4*)&rs[q * 4];
            d0 += rr[q].x * w4.x; d1 += rr[q].y * w4.y;
            d2 += rr[q].z * w4.z; d3 += rr[q].w * w4.w;
        }
        const float d = sqrtf(fmaxf(sqi + sqs - 2.0f * ((d0 + d1) + (d2 + d3)), 0.0f));
        anchor = fminf(anchor, d);

        // loop-carried register pin: rr appears modified each iteration ->
        // cannot be rematerialized from R
        #pragma unroll
        for (int q = 0; q < 32; ++q)
            asm volatile("" : "+v"(rr[q].x), "+v"(rr[q].y), "+v"(rr[q].z), "+v"(rr[q].w));
    }

    // gather: block k writes out[k] = F[idx_k]  (no LDS needed, idx in register)
    if (bid < NS) {
        #pragma unroll
        for (int p = 0; p < DIN / (BTHR * 4); ++p) {
            const int c = (p * BTHR + tid) * 4;
            *(float4*)&out[(size_t)bid * DIN + c] =
                *(const float4*)&F[(size_t)myidx * DIN + c];
        }
    }
}

extern "C" void kernel_launch(void* const* d_in, const int* in_sizes, int n_in,
                              void* d_out, int out_size, void* d_ws, size_t ws_size,
                              hipStream_t stream) {
    const float* F = (const float*)d_in[0];   // [16384,1024]
    const float* W = (const float*)d_in[1];   // [1024,128]
    float* out = (float*)d_out;               // [163,1024]

    float* R       = (float*)d_ws;                    // 16384*128 f32 = 8 MiB
    float* sq      = R + (size_t)NPTS * DP;           // 16384 f32
    float* tS      = sq + NPTS;                       // 129 f32 (pad to 132)
    float* part    = tS + 132;                        // 64*128 f32
    float* part_sq = part + 64 * DP;                  // 64 f32
    unsigned long long* gmax = (unsigned long long*)(part_sq + 64);  // NS*NBLK u64

    hipLaunchKernelGGL(k_proj, dim3(NPTS / 32), dim3(256), 0, stream, F, W, R);
    hipLaunchKernelGGL(k_sq, dim3(64), dim3(256), 0, stream, R, sq);
    hipLaunchKernelGGL(k_colpart, dim3(64), dim3(256), 0, stream, R, sq, part, part_sq, gmax);
    hipLaunchKernelGGL(k_colfin, dim3(1), dim3(256), 0, stream, part, part_sq, tS);

    const float* Rc = R; const float* sqc = sq; const float* tSc = tS; const float* Fc = F;
    unsigned long long* gm = gmax; float* op = out;
    void* args[] = { (void*)&Rc, (void*)&sqc, (void*)&tSc, (void*)&Fc,
                     (void*)&gm, (void*)&op };
    hipLaunchCooperativeKernel((const void*)k_greedy, dim3(NBLK), dim3(BTHR),
                               args, 0, stream);
}

// Round 12
// 746.970 us; speedup vs baseline: 1.2741x; 1.2741x over previous
//
#include <hip/hip_runtime.h>

#define NPTS 16384
#define DIN  1024
#define DP   128
#define NS   163
#define NBLK 64          // cooperative blocks (1 per CU)
#define BTHR 256         // threads per block -> NBLK*BTHR = NPTS, 1 point/thread
#define WPB  (BTHR / 64) // waves per block = 4

// ---------------- K1: projection GEMM  R[N,128] = F[N,1024] @ W[1024,128] (f32)
// 64x128 tile per block, 8x4 acc/thread, float4 LDS reads along k.
__global__ __launch_bounds__(256) void k_proj(const float* __restrict__ F,
                                              const float* __restrict__ W,
                                              float* __restrict__ R) {
    __shared__ float As[64][36];    // 64 rows x 32 k (+pad, 36 keeps 16B align)
    __shared__ float Bs[32][128];   // 32 k x 128 cols
    const int tid = threadIdx.x;
    const int bm  = blockIdx.x;            // 256 blocks * 64 rows
    const int lr  = tid >> 3;              // A-load row 0..31 (and +32)
    const int lc  = (tid & 7) * 4;         // A-load k-offset
    const int bkr = tid >> 5;              // B-load kk base 0..7
    const int bc  = (tid & 31) * 4;        // B-load col
    const int rg  = tid >> 5;              // 0..7 -> rows rg*8..rg*8+7
    const int cg  = tid & 31;              // cols cg*4
    const int r0  = rg * 8;
    const int c0  = cg * 4;

    float acc[8][4] = {};

    for (int k0 = 0; k0 < DIN; k0 += 32) {
        __syncthreads();
        // stage A tile: 64 rows x 32 k  (2 float4 per thread)
        *(float4*)&As[lr][lc] =
            *(const float4*)&F[(size_t)(bm * 64 + lr) * DIN + k0 + lc];
        *(float4*)&As[lr + 32][lc] =
            *(const float4*)&F[(size_t)(bm * 64 + lr + 32) * DIN + k0 + lc];
        // stage B tile: 32 k x 128 cols (4 float4 per thread)
        #pragma unroll
        for (int p = 0; p < 4; ++p) {
            const int kk = bkr + p * 8;
            *(float4*)&Bs[kk][bc] = *(const float4*)&W[(size_t)(k0 + kk) * DP + bc];
        }
        __syncthreads();
        #pragma unroll
        for (int kt = 0; kt < 32; kt += 4) {
            float4 a[8], b[4];
            #pragma unroll
            for (int i = 0; i < 8; ++i) a[i] = *(const float4*)&As[r0 + i][kt];
            #pragma unroll
            for (int j = 0; j < 4; ++j) b[j] = *(const float4*)&Bs[kt + j][c0];
            #pragma unroll
            for (int i = 0; i < 8; ++i) {
                acc[i][0] += a[i].x * b[0].x; acc[i][1] += a[i].x * b[0].y;
                acc[i][2] += a[i].x * b[0].z; acc[i][3] += a[i].x * b[0].w;
                acc[i][0] += a[i].y * b[1].x; acc[i][1] += a[i].y * b[1].y;
                acc[i][2] += a[i].y * b[1].z; acc[i][3] += a[i].y * b[1].w;
                acc[i][0] += a[i].z * b[2].x; acc[i][1] += a[i].z * b[2].y;
                acc[i][2] += a[i].z * b[2].z; acc[i][3] += a[i].z * b[2].w;
                acc[i][0] += a[i].w * b[3].x; acc[i][1] += a[i].w * b[3].y;
                acc[i][2] += a[i].w * b[3].z; acc[i][3] += a[i].w * b[3].w;
            }
        }
    }
    #pragma unroll
    for (int i = 0; i < 8; ++i) {
        float4 v = make_float4(acc[i][0], acc[i][1], acc[i][2], acc[i][3]);
        *(float4*)&R[(size_t)(bm * 64 + r0 + i) * DP + c0] = v;
    }
}

// ---------------- K2: per-row squared norm sq[i] = ||R_i||^2 (wave per row)
__global__ void k_sq(const float* __restrict__ R, float* __restrict__ sq) {
    const int lane = threadIdx.x & 63;
    const int wave = (blockIdx.x * blockDim.x + threadIdx.x) >> 6;  // 0..255
    for (int row = wave; row < NPTS; row += 256) {
        const float a = R[(size_t)row * DP + lane];
        const float b = R[(size_t)row * DP + 64 + lane];
        float v = a * a + b * b;
        #pragma unroll
        for (int off = 32; off; off >>= 1) v += __shfl_xor(v, off);
        if (lane == 0) sq[row] = v;
    }
}

// ---------------- K3a: coalesced partial col sums over 256-row slabs; also clears gmax
__global__ __launch_bounds__(256) void k_colpart(const float* __restrict__ R,
                                                 const float* __restrict__ sq,
                                                 float* __restrict__ part,
                                                 float* __restrict__ part_sq,
                                                 unsigned long long* __restrict__ gmax) {
    const int b = blockIdx.x, tid = threadIdx.x;

    // clear the greedy slots (64 blocks x 256 threads = 16384 >= NS*NBLK)
    const int slot = b * 256 + tid;
    if (slot < NS * NBLK) gmax[slot] = 0ull;

    if (tid < DP) {
        float acc = 0.0f;
        const float* p = R + (size_t)b * 256 * DP + tid;
        #pragma unroll 8
        for (int r = 0; r < 256; ++r) acc += p[(size_t)r * DP];
        part[b * DP + tid] = acc;
    } else if (tid < 192) {
        const int lane = tid - 128;   // wave 2: partial sum of sq over the slab
        const float* s = sq + b * 256;
        float v = s[lane] + s[64 + lane] + s[128 + lane] + s[192 + lane];
        #pragma unroll
        for (int off = 32; off; off >>= 1) v += __shfl_xor(v, off);
        if (lane == 0) part_sq[b] = v;
    }
}

// ---------------- K3b: final deterministic reduction of partials
__global__ void k_colfin(const float* __restrict__ part, const float* __restrict__ part_sq,
                         float* __restrict__ tS) {
    const int tid = threadIdx.x;
    if (tid < DP) {
        float acc = 0.0f;
        #pragma unroll 8
        for (int b = 0; b < 64; ++b) acc += part[b * DP + tid];
        tS[tid] = acc;
    } else if (tid == DP) {
        float s = 0.0f;
        #pragma unroll
        for (int b = 0; b < 64; ++b) s += part_sq[b];
        tS[DP] = s;
    }
}

// ---------------- K4: greedy FPS loop; single poll wave + sleep backoff
// (VERBATIM copy of the Round-4 passing kernel — do not touch)
__global__ __launch_bounds__(BTHR, 1) void k_greedy(
    const float* __restrict__ R, const float* __restrict__ sq,
    const float* __restrict__ tS, const float* __restrict__ F,
    unsigned long long* gmax, float* __restrict__ out) {
    __shared__ unsigned long long lmax[WPB];
    __shared__ unsigned sidx_cur;
    __shared__ unsigned sidx[(NS + NBLK - 1) / NBLK];   // 3

    const int tid  = threadIdx.x;
    const int lane = tid & 63;
    const int wid  = tid >> 6;
    const int bid  = blockIdx.x;
    const int g    = bid * BTHR + tid;          // my point id, 0..16383

    // own projected row in registers (32 x float4 = 128 VGPRs)
    float4 rr[32];
    #pragma unroll
    for (int q = 0; q < 32; ++q) rr[q] = *(const float4*)&R[(size_t)g * DP + q * 4];
    const float sqi = sq[g];

    // anchor0 = sqrt(N*sq_i + S - 2*r_i.t)  (common terms preserve ranking)
    float a0 = 0.f, a1 = 0.f, a2 = 0.f, a3 = 0.f;
    #pragma unroll
    for (int q = 0; q < 32; ++q) {
        const float4 t4 = *(const float4*)&tS[q * 4];
        a0 += rr[q].x * t4.x; a1 += rr[q].y * t4.y;
        a2 += rr[q].z * t4.z; a3 += rr[q].w * t4.w;
    }
    const float S = tS[DP];
    float anchor = sqrtf(fmaxf((float)NPTS * sqi + S - 2.0f * ((a0 + a1) + (a2 + a3)), 0.0f));

    for (int k = 0; k < NS; ++k) {
        // key = (bits(anchor)<<32) | (~g): max-key == first-occurrence argmax; never 0
        unsigned long long key =
            ((unsigned long long)__float_as_uint(anchor) << 32) |
            (unsigned long long)(0xFFFFFFFFu - (unsigned)g);
        #pragma unroll
        for (int off = 32; off; off >>= 1) {
            const unsigned long long o = __shfl_xor(key, off);
            key = (o > key) ? o : key;
        }
        if (lane == 0) lmax[wid] = key;
        __syncthreads();

        if (wid == 0) {
            if (lane == 0) {
                unsigned long long bk = lmax[0];
                #pragma unroll
                for (int w = 1; w < WPB; ++w) bk = (lmax[w] > bk) ? lmax[w] : bk;
                __hip_atomic_store(&gmax[(size_t)k * NBLK + bid], bk,
                                   __ATOMIC_RELAXED, __HIP_MEMORY_SCOPE_AGENT);
            }
            // only wave 0 polls: 64 pollers GPU-wide, sleep backoff cuts LLC pressure
            const unsigned long long* gs = &gmax[(size_t)k * NBLK];
            unsigned long long v =
                __hip_atomic_load(&gs[lane], __ATOMIC_RELAXED, __HIP_MEMORY_SCOPE_AGENT);
            while (!__all(v != 0ull)) {
                __builtin_amdgcn_s_sleep(2);
                v = __hip_atomic_load(&gs[lane], __ATOMIC_RELAXED, __HIP_MEMORY_SCOPE_AGENT);
            }
            #pragma unroll
            for (int off = 32; off; off >>= 1) {
                const unsigned long long o = __shfl_xor(v, off);
                v = (o > v) ? o : v;
            }
            if (lane == 0) {
                const unsigned idx = 0xFFFFFFFFu - (unsigned)(v & 0xFFFFFFFFull);
                sidx_cur = idx;
                if ((k & 63) == bid) sidx[k >> 6] = idx;
            }
        }
        __syncthreads();
        const unsigned idx = sidx_cur;

        // anchor = min(anchor, dist(g, idx)); selected row via L1-broadcast loads
        const float sqs = sq[idx];
        const float* rs = &R[(size_t)idx * DP];
        float d0 = 0.f, d1 = 0.f, d2 = 0.f, d3 = 0.f;
        #pragma unroll
        for (int q = 0; q < 32; ++q) {
            const float4 w4 = *(const float4*)&rs[q * 4];
            d0 += rr[q].x * w4.x; d1 += rr[q].y * w4.y;
            d2 += rr[q].z * w4.z; d3 += rr[q].w * w4.w;
        }
        const float d = sqrtf(fmaxf(sqi + sqs - 2.0f * ((d0 + d1) + (d2 + d3)), 0.0f));
        anchor = fminf(anchor, d);

        // loop-carried register pin: rr appears modified -> cannot be
        // rematerialized from R, must stay resident in VGPRs
        #pragma unroll
        for (int q = 0; q < 32; ++q)
            asm volatile("" : "+v"(rr[q].x), "+v"(rr[q].y), "+v"(rr[q].z), "+v"(rr[q].w));
    }

    __syncthreads();
    // gather: block b owns k = b, b+64, b+128 (indices recorded in sidx)
    #pragma unroll
    for (int q = 0; q < 3; ++q) {
        const int k = q * NBLK + bid;
        if (k < NS) {
            const unsigned idx = sidx[q];
            *(float4*)&out[(size_t)k * DIN + tid * 4] =
                *(const float4*)&F[(size_t)idx * DIN + tid * 4];
        }
    }
}

extern "C" void kernel_launch(void* const* d_in, const int* in_sizes, int n_in,
                              void* d_out, int out_size, void* d_ws, size_t ws_size,
                              hipStream_t stream) {
    const float* F = (const float*)d_in[0];   // [16384,1024]
    const float* W = (const float*)d_in[1];   // [1024,128]
    float* out = (float*)d_out;               // [163,1024]

    float* R       = (float*)d_ws;                    // 16384*128 f32 = 8 MiB
    float* sq      = R + (size_t)NPTS * DP;           // 16384 f32
    float* tS      = sq + NPTS;                       // 129 f32 (pad to 132)
    float* part    = tS + 132;                        // 64*128 f32
    float* part_sq = part + 64 * DP;                  // 64 f32
    unsigned long long* gmax = (unsigned long long*)(part_sq + 64);  // NS*NBLK u64

    hipLaunchKernelGGL(k_proj, dim3(NPTS / 64), dim3(256), 0, stream, F, W, R);
    hipLaunchKernelGGL(k_sq, dim3(64), dim3(256), 0, stream, R, sq);
    hipLaunchKernelGGL(k_colpart, dim3(64), dim3(256), 0, stream, R, sq, part, part_sq, gmax);
    hipLaunchKernelGGL(k_colfin, dim3(1), dim3(256), 0, stream, part, part_sq, tS);

    const float* Rc = R; const float* sqc = sq; const float* tSc = tS; const float* Fc = F;
    unsigned long long* gm = gmax; float* op = out;
    void* args[] = { (void*)&Rc, (void*)&sqc, (void*)&tSc, (void*)&Fc,
                     (void*)&gm, (void*)&op };
    hipLaunchCooperativeKernel((const void*)k_greedy, dim3(NBLK), dim3(BTHR),
                               args, 0, stream);
}

// Round 13
// 746.457 us; speedup vs baseline: 1.2750x; 1.0007x over previous
//
#include <hip/hip_runtime.h>

#define NPTS 16384
#define DIN  1024
#define DP   128
#define NS   163
#define NBLK 64          // cooperative blocks (1 per CU)
#define BTHR 256         // threads per block -> NBLK*BTHR = NPTS, 1 point/thread
#define WPB  (BTHR / 64) // waves per block = 4

// ---------------- K1: projection GEMM  R[N,128] = F[N,1024] @ W[1024,128] (f32)
// 64x128 tile per block, 8x4 acc/thread, float4 LDS reads along k.
__global__ __launch_bounds__(256) void k_proj(const float* __restrict__ F,
                                              const float* __restrict__ W,
                                              float* __restrict__ R) {
    __shared__ float As[64][36];    // 64 rows x 32 k (+pad, 36 keeps 16B align)
    __shared__ float Bs[32][128];   // 32 k x 128 cols
    const int tid = threadIdx.x;
    const int bm  = blockIdx.x;            // 256 blocks * 64 rows
    const int lr  = tid >> 3;              // A-load row 0..31 (and +32)
    const int lc  = (tid & 7) * 4;         // A-load k-offset
    const int bkr = tid >> 5;              // B-load kk base 0..7
    const int bc  = (tid & 31) * 4;        // B-load col
    const int rg  = tid >> 5;              // 0..7 -> rows rg*8..rg*8+7
    const int cg  = tid & 31;              // cols cg*4
    const int r0  = rg * 8;
    const int c0  = cg * 4;

    float acc[8][4] = {};

    for (int k0 = 0; k0 < DIN; k0 += 32) {
        __syncthreads();
        // stage A tile: 64 rows x 32 k  (2 float4 per thread)
        *(float4*)&As[lr][lc] =
            *(const float4*)&F[(size_t)(bm * 64 + lr) * DIN + k0 + lc];
        *(float4*)&As[lr + 32][lc] =
            *(const float4*)&F[(size_t)(bm * 64 + lr + 32) * DIN + k0 + lc];
        // stage B tile: 32 k x 128 cols (4 float4 per thread)
        #pragma unroll
        for (int p = 0; p < 4; ++p) {
            const int kk = bkr + p * 8;
            *(float4*)&Bs[kk][bc] = *(const float4*)&W[(size_t)(k0 + kk) * DP + bc];
        }
        __syncthreads();
        #pragma unroll
        for (int kt = 0; kt < 32; kt += 4) {
            float4 a[8], b[4];
            #pragma unroll
            for (int i = 0; i < 8; ++i) a[i] = *(const float4*)&As[r0 + i][kt];
            #pragma unroll
            for (int j = 0; j < 4; ++j) b[j] = *(const float4*)&Bs[kt + j][c0];
            #pragma unroll
            for (int i = 0; i < 8; ++i) {
                acc[i][0] += a[i].x * b[0].x; acc[i][1] += a[i].x * b[0].y;
                acc[i][2] += a[i].x * b[0].z; acc[i][3] += a[i].x * b[0].w;
                acc[i][0] += a[i].y * b[1].x; acc[i][1] += a[i].y * b[1].y;
                acc[i][2] += a[i].y * b[1].z; acc[i][3] += a[i].y * b[1].w;
                acc[i][0] += a[i].z * b[2].x; acc[i][1] += a[i].z * b[2].y;
                acc[i][2] += a[i].z * b[2].z; acc[i][3] += a[i].z * b[2].w;
                acc[i][0] += a[i].w * b[3].x; acc[i][1] += a[i].w * b[3].y;
                acc[i][2] += a[i].w * b[3].z; acc[i][3] += a[i].w * b[3].w;
            }
        }
    }
    #pragma unroll
    for (int i = 0; i < 8; ++i) {
        float4 v = make_float4(acc[i][0], acc[i][1], acc[i][2], acc[i][3]);
        *(float4*)&R[(size_t)(bm * 64 + r0 + i) * DP + c0] = v;
    }
}

// ---------------- K2: per-row squared norm sq[i] = ||R_i||^2 (wave per row)
__global__ void k_sq(const float* __restrict__ R, float* __restrict__ sq) {
    const int lane = threadIdx.x & 63;
    const int wave = (blockIdx.x * blockDim.x + threadIdx.x) >> 6;  // 0..255
    for (int row = wave; row < NPTS; row += 256) {
        const float a = R[(size_t)row * DP + lane];
        const float b = R[(size_t)row * DP + 64 + lane];
        float v = a * a + b * b;
        #pragma unroll
        for (int off = 32; off; off >>= 1) v += __shfl_xor(v, off);
        if (lane == 0) sq[row] = v;
    }
}

// ---------------- K3a: coalesced partial col sums over 256-row slabs; also clears gmax
__global__ __launch_bounds__(256) void k_colpart(const float* __restrict__ R,
                                                 const float* __restrict__ sq,
                                                 float* __restrict__ part,
                                                 float* __restrict__ part_sq,
                                                 unsigned long long* __restrict__ gmax) {
    const int b = blockIdx.x, tid = threadIdx.x;

    // clear the greedy slots (64 blocks x 256 threads = 16384 >= NS*NBLK)
    const int slot = b * 256 + tid;
    if (slot < NS * NBLK) gmax[slot] = 0ull;

    if (tid < DP) {
        float acc = 0.0f;
        const float* p = R + (size_t)b * 256 * DP + tid;
        #pragma unroll 8
        for (int r = 0; r < 256; ++r) acc += p[(size_t)r * DP];
        part[b * DP + tid] = acc;
    } else if (tid < 192) {
        const int lane = tid - 128;   // wave 2: partial sum of sq over the slab
        const float* s = sq + b * 256;
        float v = s[lane] + s[64 + lane] + s[128 + lane] + s[192 + lane];
        #pragma unroll
        for (int off = 32; off; off >>= 1) v += __shfl_xor(v, off);
        if (lane == 0) part_sq[b] = v;
    }
}

// ---------------- K3b: final deterministic reduction of partials
__global__ void k_colfin(const float* __restrict__ part, const float* __restrict__ part_sq,
                         float* __restrict__ tS) {
    const int tid = threadIdx.x;
    if (tid < DP) {
        float acc = 0.0f;
        #pragma unroll 8
        for (int b = 0; b < 64; ++b) acc += part[b * DP + tid];
        tS[tid] = acc;
    } else if (tid == DP) {
        float s = 0.0f;
        #pragma unroll
        for (int b = 0; b < 64; ++b) s += part_sq[b];
        tS[DP] = s;
    }
}

// ---------------- K4: greedy FPS loop; single poll wave + sleep backoff
// (VERBATIM copy of the Round-4 passing kernel — do not touch)
__global__ __launch_bounds__(BTHR, 1) void k_greedy(
    const float* __restrict__ R, const float* __restrict__ sq,
    const float* __restrict__ tS, const float* __restrict__ F,
    unsigned long long* gmax, float* __restrict__ out) {
    __shared__ unsigned long long lmax[WPB];
    __shared__ unsigned sidx_cur;
    __shared__ unsigned sidx[(NS + NBLK - 1) / NBLK];   // 3

    const int tid  = threadIdx.x;
    const int lane = tid & 63;
    const int wid  = tid >> 6;
    const int bid  = blockIdx.x;
    const int g    = bid * BTHR + tid;          // my point id, 0..16383

    // own projected row in registers (32 x float4 = 128 VGPRs)
    float4 rr[32];
    #pragma unroll
    for (int q = 0; q < 32; ++q) rr[q] = *(const float4*)&R[(size_t)g * DP + q * 4];
    const float sqi = sq[g];

    // anchor0 = sqrt(N*sq_i + S - 2*r_i.t)  (common terms preserve ranking)
    float a0 = 0.f, a1 = 0.f, a2 = 0.f, a3 = 0.f;
    #pragma unroll
    for (int q = 0; q < 32; ++q) {
        const float4 t4 = *(const float4*)&tS[q * 4];
        a0 += rr[q].x * t4.x; a1 += rr[q].y * t4.y;
        a2 += rr[q].z * t4.z; a3 += rr[q].w * t4.w;
    }
    const float S = tS[DP];
    float anchor = sqrtf(fmaxf((float)NPTS * sqi + S - 2.0f * ((a0 + a1) + (a2 + a3)), 0.0f));

    for (int k = 0; k < NS; ++k) {
        // key = (bits(anchor)<<32) | (~g): max-key == first-occurrence argmax; never 0
        unsigned long long key =
            ((unsigned long long)__float_as_uint(anchor) << 32) |
            (unsigned long long)(0xFFFFFFFFu - (unsigned)g);
        #pragma unroll
        for (int off = 32; off; off >>= 1) {
            const unsigned long long o = __shfl_xor(key, off);
            key = (o > key) ? o : key;
        }
        if (lane == 0) lmax[wid] = key;
        __syncthreads();

        if (wid == 0) {
            if (lane == 0) {
                unsigned long long bk = lmax[0];
                #pragma unroll
                for (int w = 1; w < WPB; ++w) bk = (lmax[w] > bk) ? lmax[w] : bk;
                __hip_atomic_store(&gmax[(size_t)k * NBLK + bid], bk,
                                   __ATOMIC_RELAXED, __HIP_MEMORY_SCOPE_AGENT);
            }
            // only wave 0 polls: 64 pollers GPU-wide, sleep backoff cuts LLC pressure
            const unsigned long long* gs = &gmax[(size_t)k * NBLK];
            unsigned long long v =
                __hip_atomic_load(&gs[lane], __ATOMIC_RELAXED, __HIP_MEMORY_SCOPE_AGENT);
            while (!__all(v != 0ull)) {
                __builtin_amdgcn_s_sleep(2);
                v = __hip_atomic_load(&gs[lane], __ATOMIC_RELAXED, __HIP_MEMORY_SCOPE_AGENT);
            }
            #pragma unroll
            for (int off = 32; off; off >>= 1) {
                const unsigned long long o = __shfl_xor(v, off);
                v = (o > v) ? o : v;
            }
            if (lane == 0) {
                const unsigned idx = 0xFFFFFFFFu - (unsigned)(v & 0xFFFFFFFFull);
                sidx_cur = idx;
                if ((k & 63) == bid) sidx[k >> 6] = idx;
            }
        }
        __syncthreads();
        const unsigned idx = sidx_cur;

        // anchor = min(anchor, dist(g, idx)); selected row via L1-broadcast loads
        const float sqs = sq[idx];
        const float* rs = &R[(size_t)idx * DP];
        float d0 = 0.f, d1 = 0.f, d2 = 0.f, d3 = 0.f;
        #pragma unroll
        for (int q = 0; q < 32; ++q) {
            const float4 w4 = *(const float4*)&rs[q * 4];
            d0 += rr[q].x * w4.x; d1 += rr[q].y * w4.y;
            d2 += rr[q].z * w4.z; d3 += rr[q].w * w4.w;
        }
        const float d = sqrtf(fmaxf(sqi + sqs - 2.0f * ((d0 + d1) + (d2 + d3)), 0.0f));
        anchor = fminf(anchor, d);

        // loop-carried register pin: rr appears modified -> cannot be
        // rematerialized from R, must stay resident in VGPRs
        #pragma unroll
        for (int q = 0; q < 32; ++q)
            asm volatile("" : "+v"(rr[q].x), "+v"(rr[q].y), "+v"(rr[q].z), "+v"(rr[q].w));
    }

    __syncthreads();
    // gather: block b owns k = b, b+64, b+128 (indices recorded in sidx)
    #pragma unroll
    for (int q = 0; q < 3; ++q) {
        const int k = q * NBLK + bid;
        if (k < NS) {
            const unsigned idx = sidx[q];
            *(float4*)&out[(size_t)k * DIN + tid * 4] =
                *(const float4*)&F[(size_t)idx * DIN + tid * 4];
        }
    }
}

extern "C" void kernel_launch(void* const* d_in, const int* in_sizes, int n_in,
                              void* d_out, int out_size, void* d_ws, size_t ws_size,
                              hipStream_t stream) {
    const float* F = (const float*)d_in[0];   // [16384,1024]
    const float* W = (const float*)d_in[1];   // [1024,128]
    float* out = (float*)d_out;               // [163,1024]

    float* R       = (float*)d_ws;                    // 16384*128 f32 = 8 MiB
    float* sq      = R + (size_t)NPTS * DP;           // 16384 f32
    float* tS      = sq + NPTS;                       // 129 f32 (pad to 132)
    float* part    = tS + 132;                        // 64*128 f32
    float* part_sq = part + 64 * DP;                  // 64 f32
    unsigned long long* gmax = (unsigned long long*)(part_sq + 64);  // NS*NBLK u64

    hipLaunchKernelGGL(k_proj, dim3(NPTS / 64), dim3(256), 0, stream, F, W, R);
    hipLaunchKernelGGL(k_sq, dim3(64), dim3(256), 0, stream, R, sq);
    hipLaunchKernelGGL(k_colpart, dim3(64), dim3(256), 0, stream, R, sq, part, part_sq, gmax);
    hipLaunchKernelGGL(k_colfin, dim3(1), dim3(256), 0, stream, part, part_sq, tS);

    const float* Rc = R; const float* sqc = sq; const float* tSc = tS; const float* Fc = F;
    unsigned long long* gm = gmax; float* op = out;
    void* args[] = { (void*)&Rc, (void*)&sqc, (void*)&tSc, (void*)&Fc,
                     (void*)&gm, (void*)&op };
    hipLaunchCooperativeKernel((const void*)k_greedy, dim3(NBLK), dim3(BTHR),
                               args, 0, stream);
}

// Round 14
// 594.502 us; speedup vs baseline: 1.6008x; 1.2556x over previous
//
#include <hip/hip_runtime.h>

#define NPTS 16384
#define DIN  1024
#define DP   128
#define NS   163
#define NBLK 64          // cooperative blocks (1 per CU)
#define BTHR 256         // threads per block -> NBLK*BTHR = NPTS, 1 point/thread
#define WPB  (BTHR / 64) // waves per block = 4
#define CMARGIN 1e-3f    // certification margin (covers cross-order ulp skew)

typedef unsigned long long u64;
typedef unsigned int u32;

// ---------------- K1: projection GEMM  R[N,128] = F[N,1024] @ W[1024,128] (f32)
// (R4-passing version, verbatim)
__global__ __launch_bounds__(256) void k_proj(const float* __restrict__ F,
                                              const float* __restrict__ W,
                                              float* __restrict__ R) {
    __shared__ float As[32][36];
    __shared__ float Bs[32][128];
    const int tid = threadIdx.x;
    const int bm  = blockIdx.x;
    const int lr  = tid >> 3;
    const int lc  = (tid & 7) * 4;
    const int bkr = tid >> 5;
    const int bc  = (tid & 31) * 4;
    const int r0  = (tid >> 5) * 4;
    const int c0  = (tid & 31) * 4;

    float acc[4][4] = {};

    for (int k0 = 0; k0 < DIN; k0 += 32) {
        __syncthreads();
        *(float4*)&As[lr][lc] =
            *(const float4*)&F[(size_t)(bm * 32 + lr) * DIN + k0 + lc];
        #pragma unroll
        for (int p = 0; p < 4; ++p) {
            const int kk = bkr + p * 8;
            *(float4*)&Bs[kk][bc] = *(const float4*)&W[(size_t)(k0 + kk) * DP + bc];
        }
        __syncthreads();
        #pragma unroll
        for (int kt = 0; kt < 32; kt += 4) {
            float4 a[4], b[4];
            #pragma unroll
            for (int i = 0; i < 4; ++i) a[i] = *(const float4*)&As[r0 + i][kt];
            #pragma unroll
            for (int j = 0; j < 4; ++j) b[j] = *(const float4*)&Bs[kt + j][c0];
            #pragma unroll
            for (int i = 0; i < 4; ++i) {
                acc[i][0] += a[i].x * b[0].x; acc[i][1] += a[i].x * b[0].y;
                acc[i][2] += a[i].x * b[0].z; acc[i][3] += a[i].x * b[0].w;
                acc[i][0] += a[i].y * b[1].x; acc[i][1] += a[i].y * b[1].y;
                acc[i][2] += a[i].y * b[1].z; acc[i][3] += a[i].y * b[1].w;
                acc[i][0] += a[i].z * b[2].x; acc[i][1] += a[i].z * b[2].y;
                acc[i][2] += a[i].z * b[2].z; acc[i][3] += a[i].z * b[2].w;
                acc[i][0] += a[i].w * b[3].x; acc[i][1] += a[i].w * b[3].y;
                acc[i][2] += a[i].w * b[3].z; acc[i][3] += a[i].w * b[3].w;
            }
        }
    }
    #pragma unroll
    for (int i = 0; i < 4; ++i) {
        float4 v = make_float4(acc[i][0], acc[i][1], acc[i][2], acc[i][3]);
        *(float4*)&R[(size_t)(bm * 32 + r0 + i) * DP + c0] = v;
    }
}

// ---------------- K2: per-row squared norm sq[i] = ||R_i||^2 (wave per row)
__global__ void k_sq(const float* __restrict__ R, float* __restrict__ sq) {
    const int lane = threadIdx.x & 63;
    const int wave = (blockIdx.x * blockDim.x + threadIdx.x) >> 6;
    for (int row = wave; row < NPTS; row += 256) {
        const float a = R[(size_t)row * DP + lane];
        const float b = R[(size_t)row * DP + 64 + lane];
        float v = a * a + b * b;
        #pragma unroll
        for (int off = 32; off; off >>= 1) v += __shfl_xor(v, off);
        if (lane == 0) sq[row] = v;
    }
}

// ---------------- K3a: coalesced partial col sums; also clears gmax (4 slots/block/round)
__global__ __launch_bounds__(256) void k_colpart(const float* __restrict__ R,
                                                 const float* __restrict__ sq,
                                                 float* __restrict__ part,
                                                 float* __restrict__ part_sq,
                                                 u64* __restrict__ gmax) {
    const int b = blockIdx.x, tid = threadIdx.x;
    const int gt = b * 256 + tid;

    for (int s = gt; s < NS * NBLK * 4; s += 64 * 256) gmax[s] = 0ull;

    if (tid < DP) {
        float acc = 0.0f;
        const float* p = R + (size_t)b * 256 * DP + tid;
        #pragma unroll 8
        for (int r = 0; r < 256; ++r) acc += p[(size_t)r * DP];
        part[b * DP + tid] = acc;
    } else if (tid < 192) {
        const int lane = tid - 128;
        const float* s = sq + b * 256;
        float v = s[lane] + s[64 + lane] + s[128 + lane] + s[192 + lane];
        #pragma unroll
        for (int off = 32; off; off >>= 1) v += __shfl_xor(v, off);
        if (lane == 0) part_sq[b] = v;
    }
}

// ---------------- K3b: final deterministic reduction of partials
__global__ void k_colfin(const float* __restrict__ part, const float* __restrict__ part_sq,
                         float* __restrict__ tS) {
    const int tid = threadIdx.x;
    if (tid < DP) {
        float acc = 0.0f;
        #pragma unroll 8
        for (int b = 0; b < 64; ++b) acc += part[b * DP + tid];
        tS[tid] = acc;
    } else if (tid == DP) {
        float s = 0.0f;
        #pragma unroll
        for (int b = 0; b < 64; ++b) s += part_sq[b];
        tS[DP] = s;
    }
}

__device__ __forceinline__ u64 wavemax_u64(u64 k) {
    #pragma unroll
    for (int off = 32; off; off >>= 1) {
        const u64 o = __shfl_xor(k, off);
        k = (o > k) ? o : k;
    }
    return k;
}

__device__ __forceinline__ float wsum_f32(float v) {
    #pragma unroll
    for (int off = 32; off; off >>= 1) v += __shfl_xor(v, off);
    return v;
}

// ---------------- K4: greedy FPS with certified multi-select (chain <= 4/round).
// R4 skeleton: publish (now top-4) + wave-0-only poll + LDS broadcast.
__global__ __launch_bounds__(BTHR, 1) void k_greedy(
    const float* __restrict__ R, const float* __restrict__ sq,
    const float* __restrict__ tS, const float* __restrict__ F,
    u64* gmax, float* __restrict__ out) {
    __shared__ u64 lmax[WPB][4];
    __shared__ u32 bc_idx[4];
    __shared__ u32 bc_cnt;
    __shared__ u32 sidx[(NS + NBLK - 1) / NBLK];   // 3

    const int tid  = threadIdx.x;
    const int lane = tid & 63;
    const int wid  = tid >> 6;
    const int bid  = blockIdx.x;
    const int g    = bid * BTHR + tid;          // my point id

    float4 rr[32];
    #pragma unroll
    for (int q = 0; q < 32; ++q) rr[q] = *(const float4*)&R[(size_t)g * DP + q * 4];
    const float sqi = sq[g];

    // anchor0 = sqrt(N*sq_i + S - 2*r_i.t)  (common terms preserve ranking)
    float a0 = 0.f, a1 = 0.f, a2 = 0.f, a3 = 0.f;
    #pragma unroll
    for (int q = 0; q < 32; ++q) {
        const float4 t4 = *(const float4*)&tS[q * 4];
        a0 += rr[q].x * t4.x; a1 += rr[q].y * t4.y;
        a2 += rr[q].z * t4.z; a3 += rr[q].w * t4.w;
    }
    const float S = tS[DP];
    float anchor = sqrtf(fmaxf((float)NPTS * sqi + S - 2.0f * ((a0 + a1) + (a2 + a3)), 0.0f));

    int nsel = 0, r = 0;

    while (nsel < NS) {
        // ---- publish: block top-4 keys (key never 0; unique per point)
        const u64 key =
            ((u64)__float_as_uint(anchor) << 32) |
            (u64)(0xFFFFFFFFu - (unsigned)g);
        u64 kx = key;
        const u64 k1 = wavemax_u64(kx); kx = (kx == k1) ? 0ull : kx;
        const u64 k2 = wavemax_u64(kx); kx = (kx == k2) ? 0ull : kx;
        const u64 k3 = wavemax_u64(kx); kx = (kx == k3) ? 0ull : kx;
        const u64 k4 = wavemax_u64(kx);
        if (lane == 0) { lmax[wid][0] = k1; lmax[wid][1] = k2; lmax[wid][2] = k3; lmax[wid][3] = k4; }
        __syncthreads();

        if (wid == 0) {
            if (lane == 0) {
                u64 t0 = 0, t1 = 0, t2 = 0, t3 = 0;
                #pragma unroll
                for (int w = 0; w < WPB; ++w) {
                    #pragma unroll
                    for (int j = 0; j < 4; ++j) {
                        const u64 v = lmax[w][j];
                        if (v > t0)      { t3 = t2; t2 = t1; t1 = t0; t0 = v; }
                        else if (v > t1) { t3 = t2; t2 = t1; t1 = v; }
                        else if (v > t2) { t3 = t2; t2 = v; }
                        else if (v > t3) { t3 = v; }
                    }
                }
                u64* dst = &gmax[((size_t)r * NBLK + bid) * 4];
                __hip_atomic_store(&dst[0], t0, __ATOMIC_RELAXED, __HIP_MEMORY_SCOPE_AGENT);
                __hip_atomic_store(&dst[1], t1, __ATOMIC_RELAXED, __HIP_MEMORY_SCOPE_AGENT);
                __hip_atomic_store(&dst[2], t2, __ATOMIC_RELAXED, __HIP_MEMORY_SCOPE_AGENT);
                __hip_atomic_store(&dst[3], t3, __ATOMIC_RELAXED, __HIP_MEMORY_SCOPE_AGENT);
            }
            // ---- poll all 256 slots (wave 0 only, sleep backoff)
            const u64* gs = &gmax[(size_t)r * NBLK * 4];
            u64 v0, v1, v2, v3;
            v0 = __hip_atomic_load(&gs[lane      ], __ATOMIC_RELAXED, __HIP_MEMORY_SCOPE_AGENT);
            v1 = __hip_atomic_load(&gs[lane +  64], __ATOMIC_RELAXED, __HIP_MEMORY_SCOPE_AGENT);
            v2 = __hip_atomic_load(&gs[lane + 128], __ATOMIC_RELAXED, __HIP_MEMORY_SCOPE_AGENT);
            v3 = __hip_atomic_load(&gs[lane + 192], __ATOMIC_RELAXED, __HIP_MEMORY_SCOPE_AGENT);
            while (!__all((v0 != 0ull) & (v1 != 0ull) & (v2 != 0ull) & (v3 != 0ull))) {
                __builtin_amdgcn_s_sleep(2);
                v0 = __hip_atomic_load(&gs[lane      ], __ATOMIC_RELAXED, __HIP_MEMORY_SCOPE_AGENT);
                v1 = __hip_atomic_load(&gs[lane +  64], __ATOMIC_RELAXED, __HIP_MEMORY_SCOPE_AGENT);
                v2 = __hip_atomic_load(&gs[lane + 128], __ATOMIC_RELAXED, __HIP_MEMORY_SCOPE_AGENT);
                v3 = __hip_atomic_load(&gs[lane + 192], __ATOMIC_RELAXED, __HIP_MEMORY_SCOPE_AGENT);
            }

            // B4 = max over blocks' 4th entries (slot%4==3 <=> lane%4==3)
            u64 vm = v0; if (v1 > vm) vm = v1; if (v2 > vm) vm = v2; if (v3 > vm) vm = v3;
            const u64 b4 = wavemax_u64(((lane & 3) == 3) ? vm : 0ull);

            // global top-5 by masked reduces
            u64 w0 = v0, w1 = v1, w2 = v2, w3 = v3;
            u64 e0, e1, e2, e3, e4;
            {
                u64 m;
                #define GTOP(EOUT)                                            \
                    m = w0; if (w1 > m) m = w1; if (w2 > m) m = w2;           \
                    if (w3 > m) m = w3; m = wavemax_u64(m); EOUT = m;         \
                    w0 = (w0 == m) ? 0ull : w0; w1 = (w1 == m) ? 0ull : w1;   \
                    w2 = (w2 == m) ? 0ull : w2; w3 = (w3 == m) ? 0ull : w3;
                GTOP(e0) GTOP(e1) GTOP(e2) GTOP(e3) GTOP(e4)
                #undef GTOP
            }
            const u64 Uk  = (e4 > b4) ? e4 : b4;
            const float Uf = __uint_as_float((u32)(Uk >> 32));

            // candidate data: idx, anchor float, sq, row fragment (2 dims/lane)
            const u32 ci0 = 0xFFFFFFFFu - (u32)(e0 & 0xFFFFFFFFull);
            const u32 ci1 = 0xFFFFFFFFu - (u32)(e1 & 0xFFFFFFFFull);
            const u32 ci2 = 0xFFFFFFFFu - (u32)(e2 & 0xFFFFFFFFull);
            const u32 ci3 = 0xFFFFFFFFu - (u32)(e3 & 0xFFFFFFFFull);
            const float ca1 = __uint_as_float((u32)(e1 >> 32));
            const float ca2 = __uint_as_float((u32)(e2 >> 32));
            const float ca3 = __uint_as_float((u32)(e3 >> 32));
            const float2 f0 = *(const float2*)&R[(size_t)ci0 * DP + 2 * lane];
            const float2 f1 = *(const float2*)&R[(size_t)ci1 * DP + 2 * lane];
            const float2 f2 = *(const float2*)&R[(size_t)ci2 * DP + 2 * lane];
            const float2 f3 = *(const float2*)&R[(size_t)ci3 * DP + 2 * lane];
            const float s0 = sq[ci0], s1 = sq[ci1], s2 = sq[ci2], s3 = sq[ci3];

            // pairwise distances among the 4 candidates
            const float p01 = wsum_f32(f0.x * f1.x + f0.y * f1.y);
            const float p02 = wsum_f32(f0.x * f2.x + f0.y * f2.y);
            const float p03 = wsum_f32(f0.x * f3.x + f0.y * f3.y);
            const float p12 = wsum_f32(f1.x * f2.x + f1.y * f2.y);
            const float p13 = wsum_f32(f1.x * f3.x + f1.y * f3.y);
            const float p23 = wsum_f32(f2.x * f3.x + f2.y * f3.y);
            const float d01 = sqrtf(fmaxf(s0 + s1 - 2.0f * p01, 0.0f));
            const float d02 = sqrtf(fmaxf(s0 + s2 - 2.0f * p02, 0.0f));
            const float d03 = sqrtf(fmaxf(s0 + s3 - 2.0f * p03, 0.0f));
            const float d12 = sqrtf(fmaxf(s1 + s2 - 2.0f * p12, 0.0f));
            const float d13 = sqrtf(fmaxf(s1 + s3 - 2.0f * p13, 0.0f));
            const float d23 = sqrtf(fmaxf(s2 + s3 - 2.0f * p23, 0.0f));

            // certified chain (scalar, unrolled; conservative margin)
            float u1 = fminf(ca1, d01), u2 = fminf(ca2, d02), u3 = fminf(ca3, d03);
            bool  l1 = true, l2 = true, l3 = true;
            u32 o1 = 0, o2 = 0, o3 = 0;
            int cnt = 1;
            #pragma unroll
            for (int step = 0; step < 3; ++step) {
                if (nsel + cnt >= NS) break;
                int jb = 0; float bf = -1.0f; u32 bidx = 0;
                if (l1 && (u1 > bf || (u1 == bf && ci1 < bidx))) { bf = u1; bidx = ci1; jb = 1; }
                if (l2 && (u2 > bf || (u2 == bf && ci2 < bidx))) { bf = u2; bidx = ci2; jb = 2; }
                if (l3 && (u3 > bf || (u3 == bf && ci3 < bidx))) { bf = u3; bidx = ci3; jb = 3; }
                if (jb == 0 || !(bf > Uf + CMARGIN)) break;
                if (cnt == 1) o1 = bidx; else if (cnt == 2) o2 = bidx; else o3 = bidx;
                ++cnt;
                if (jb == 1)      { l1 = false; u2 = fminf(u2, d12); u3 = fminf(u3, d13); }
                else if (jb == 2) { l2 = false; u1 = fminf(u1, d12); u3 = fminf(u3, d23); }
                else              { l3 = false; u1 = fminf(u1, d13); u2 = fminf(u2, d23); }
            }
            if (lane == 0) {
                bc_idx[0] = ci0;
                if (cnt > 1) bc_idx[1] = o1;
                if (cnt > 2) bc_idx[2] = o2;
                if (cnt > 3) bc_idx[3] = o3;
                bc_cnt = (u32)cnt;
            }
        }
        __syncthreads();
        const int cnt = (int)bc_cnt;

        // ---- apply the certified batch (identical order in every block)
        for (int c = 0; c < cnt; ++c) {
            const u32 idx = bc_idx[c];
            const int kk = nsel + c;
            if (tid == 0 && (kk & 63) == bid) sidx[kk >> 6] = idx;
            const float sqs = sq[idx];
            const float* rs = &R[(size_t)idx * DP];
            float d0 = 0.f, d1 = 0.f, d2 = 0.f, d3 = 0.f;
            #pragma unroll
            for (int q = 0; q < 32; ++q) {
                const float4 w4 = *(const float4*)&rs[q * 4];
                d0 += rr[q].x * w4.x; d1 += rr[q].y * w4.y;
                d2 += rr[q].z * w4.z; d3 += rr[q].w * w4.w;
            }
            const float d = sqrtf(fmaxf(sqi + sqs - 2.0f * ((d0 + d1) + (d2 + d3)), 0.0f));
            anchor = fminf(anchor, d);
        }
        nsel += cnt;
        ++r;

        // loop-carried register pin (as in the passing R4 kernel)
        #pragma unroll
        for (int q = 0; q < 32; ++q)
            asm volatile("" : "+v"(rr[q].x), "+v"(rr[q].y), "+v"(rr[q].z), "+v"(rr[q].w));
    }

    __syncthreads();
    // gather: block b owns output rows b, b+64, b+128
    #pragma unroll
    for (int q = 0; q < 3; ++q) {
        const int k = q * NBLK + bid;
        if (k < NS) {
            const unsigned idx = sidx[q];
            *(float4*)&out[(size_t)k * DIN + tid * 4] =
                *(const float4*)&F[(size_t)idx * DIN + tid * 4];
        }
    }
}

extern "C" void kernel_launch(void* const* d_in, const int* in_sizes, int n_in,
                              void* d_out, int out_size, void* d_ws, size_t ws_size,
                              hipStream_t stream) {
    const float* F = (const float*)d_in[0];   // [16384,1024]
    const float* W = (const float*)d_in[1];   // [1024,128]
    float* out = (float*)d_out;               // [163,1024]

    float* R       = (float*)d_ws;                    // 8 MiB
    float* sq      = R + (size_t)NPTS * DP;           // 16384 f32
    float* tS      = sq + NPTS;                       // 132 f32
    float* part    = tS + 132;                        // 64*128 f32
    float* part_sq = part + 64 * DP;                  // 64 f32
    u64*   gmax    = (u64*)(part_sq + 64);            // NS*NBLK*4 u64 (~334 KB)

    hipLaunchKernelGGL(k_proj, dim3(NPTS / 32), dim3(256), 0, stream, F, W, R);
    hipLaunchKernelGGL(k_sq, dim3(64), dim3(256), 0, stream, R, sq);
    hipLaunchKernelGGL(k_colpart, dim3(64), dim3(256), 0, stream, R, sq, part, part_sq, gmax);
    hipLaunchKernelGGL(k_colfin, dim3(1), dim3(256), 0, stream, part, part_sq, tS);

    const float* Rc = R; const float* sqc = sq; const float* tSc = tS; const float* Fc = F;
    u64* gm = gmax; float* op = out;
    void* args[] = { (void*)&Rc, (void*)&sqc, (void*)&tSc, (void*)&Fc,
                     (void*)&gm, (void*)&op };
    hipLaunchCooperativeKernel((const void*)k_greedy, dim3(NBLK), dim3(BTHR),
                               args, 0, stream);
}